// Round 3
// baseline (2383.223 us; speedup 1.0000x reference)
//
#include <hip/hip_runtime.h>
#include <stdint.h>

// Problem constants (from reference)
#define ROWS 4096
#define COLS 11008
#define NTOT (ROWS * COLS)          // 45,088,768
#define NV4  (NTOT / 4)             // 11,272,192 (COLS % 4 == 0 -> float4 never crosses rows)
#define COLS4 (COLS / 4)            // 2752

// high_num = int(n*0.1); 1-indexed order-statistic ranks
#define HIGH_NUM 4508876u
#define RANK_LO  (HIGH_NUM / 2u)                   // 2,254,438
#define RANK_HI  ((unsigned)NTOT - HIGH_NUM / 2u)  // 42,834,330

#define BLK 256
#define GRID 2048

// ws layout (u32 words):
//  [0] side_count  [1] oflow  [2..3] pad
//  [4..11]  meta: (b_lo, r_lo, b_hi, r_hi)
//  [12..13] thr (2 floats)
//  [14..15] pad
//  [16 ..)          hist1[4096]
//  (.. +2048)       csum[2048]
//  (.. +2*2^20)     hist2[2*2^20]
//  then: side buffer of uint2 (idx, bits(x))
#define OFF_COUNT 0
#define OFF_OFLOW 1
#define OFF_META  4
#define OFF_THR   12
#define OFF_HIST1 16
#define OFF_CSUM  (OFF_HIST1 + 4096)
#define OFF_HIST2 (OFF_CSUM + 2048)
#define OFF_SIDE  (OFF_HIST2 + 2 * (1 << 20))   // even word offset -> uint2-aligned
#define ZERO_WORDS OFF_SIDE

__device__ __forceinline__ unsigned f2key(float f) {
    unsigned u = __float_as_uint(f);
    return (u & 0x80000000u) ? ~u : (u | 0x80000000u);
}
__device__ __forceinline__ float key2f(unsigned key) {
    unsigned u = (key & 0x80000000u) ? (key & 0x7fffffffu) : ~key;
    return __uint_as_float(u);
}

// Exact qdq, byte-identical to the passing R1 math (IEEE div + nearest-even).
__device__ __forceinline__ float qdq(float xx, bool m, float sl, float zl, float sh, float zh) {
    float s  = m ? sl : sh;
    float z  = m ? zl : zh;
    float mq = m ? 1.0f : 255.0f;
    float q = rintf(xx / s) + z;
    q = fminf(fmaxf(q, 0.0f), mq);
    return s * (q - z);
}

// ---------------- Pass 1: 4096-bucket histogram of top 12 key bits (2 parity copies) ----
__global__ void __launch_bounds__(BLK) hist12_kernel(const float* __restrict__ x,
                                                     unsigned* __restrict__ ws) {
    __shared__ unsigned h[8192];
    for (int i = threadIdx.x; i < 8192; i += BLK) h[i] = 0u;
    __syncthreads();

    const float4* x4 = (const float4*)x;
    const int par = threadIdx.x & 1;
    const int stride = GRID * BLK;
    for (int j = blockIdx.x * BLK + threadIdx.x; j < NV4; j += stride) {
        float4 v = x4[j];
        atomicAdd(&h[((f2key(v.x) >> 20) << 1) + par], 1u);
        atomicAdd(&h[((f2key(v.y) >> 20) << 1) + par], 1u);
        atomicAdd(&h[((f2key(v.z) >> 20) << 1) + par], 1u);
        atomicAdd(&h[((f2key(v.w) >> 20) << 1) + par], 1u);
    }
    __syncthreads();
    unsigned* hist1 = ws + OFF_HIST1;
    for (int i = threadIdx.x; i < 4096; i += BLK) {
        unsigned c = h[2 * i] + h[2 * i + 1];
        if (c) atomicAdd(&hist1[i], c);
    }
}

// ---------------- scan1: candidate top-12 bucket + residual rank for both targets -------
__global__ void __launch_bounds__(BLK) scan1_kernel(unsigned* __restrict__ ws) {
    __shared__ unsigned part[256];
    const unsigned* hist1 = ws + OFF_HIST1;
    unsigned* meta = ws + OFF_META;
    int t = threadIdx.x;
    unsigned v[16];
    unsigned sum = 0u;
#pragma unroll
    for (int i = 0; i < 16; i++) { v[i] = hist1[t * 16 + i]; sum += v[i]; }
    part[t] = sum;
    __syncthreads();
    for (int off = 1; off < 256; off <<= 1) {
        unsigned a = (t >= off) ? part[t - off] : 0u;
        __syncthreads();
        part[t] += a;
        __syncthreads();
    }
    unsigned incl = part[t];
    unsigned excl = incl - sum;
    unsigned ranks[2] = {RANK_LO, RANK_HI};
    for (int k = 0; k < 2; k++) {
        unsigned R = ranks[k];
        if (excl < R && incl >= R) {
            unsigned cum = excl;
            for (int i = 0; i < 16; i++) {
                if (cum + v[i] >= R) { meta[k * 2] = (unsigned)(t * 16 + i); meta[k * 2 + 1] = R - cum; break; }
                cum += v[i];
            }
        }
    }
}

// ---------------- Pass 2 (fused): hist20 on candidates + provisional quant + side list --
__global__ void __launch_bounds__(BLK) pass2_kernel(const float* __restrict__ x,
                                                    const float* __restrict__ sl_,
                                                    const float* __restrict__ zl_,
                                                    const float* __restrict__ sh_,
                                                    const float* __restrict__ zh_,
                                                    float* __restrict__ out,
                                                    unsigned* __restrict__ ws,
                                                    unsigned side_cap) {
    const unsigned b_lo = __builtin_amdgcn_readfirstlane(ws[OFF_META + 0]);
    const unsigned b_hi = __builtin_amdgcn_readfirstlane(ws[OFF_META + 2]);
    unsigned* hist2 = ws + OFF_HIST2;
    uint2* side = (uint2*)(ws + OFF_SIDE);

    const float4* x4 = (const float4*)x;
    float4* o4 = (float4*)out;
    const int stride = GRID * BLK;
    for (int j = blockIdx.x * BLK + threadIdx.x; j < NV4; j += stride) {
        int row = j / COLS4;
        float sl = sl_[row], zl = zl_[row];
        float sh = sh_[row], zh = zh_[row];
        float4 v = x4[j];
        float in[4] = {v.x, v.y, v.z, v.w};
        float r[4];
        unsigned k = 0;
        uint2 loc[4];
#pragma unroll
        for (int c = 0; c < 4; c++) {
            float xx = in[c];
            unsigned key = f2key(xx);
            unsigned top = key >> 20;
            if (top == b_lo) atomicAdd(&hist2[key & 0xFFFFFu], 1u);
            if (top == b_hi) atomicAdd(&hist2[(1u << 20) | (key & 0xFFFFFu)], 1u);
            // definite classification outside candidate buckets (key order == float order)
            bool m = (top > b_lo) && (top < b_hi);       // provisional: bulk iff strictly between
            r[c] = qdq(xx, m, sl, zl, sh, zh);
            bool amb = (top == b_lo) || (top == b_hi);
            if (amb) { loc[k] = make_uint2((unsigned)j * 4u + (unsigned)c, __float_as_uint(xx)); k++; }
        }
        o4[j] = make_float4(r[0], r[1], r[2], r[3]);
        if (k) {
            unsigned off = atomicAdd(&ws[OFF_COUNT], k);
            for (unsigned i = 0; i < k; i++) {
                if (off + i < side_cap) side[off + i] = loc[i];
                else ws[OFF_OFLOW] = 1u;
            }
        }
    }
}

// ---------------- chunksum: 1024-entry chunk sums of hist2 (2048 chunks) ----------------
__global__ void __launch_bounds__(BLK) chunksum_kernel(unsigned* __restrict__ ws) {
    const unsigned* hist2 = ws + OFF_HIST2;
    unsigned* csum = ws + OFF_CSUM;
    int t = threadIdx.x;
    const unsigned* p = hist2 + (size_t)blockIdx.x * 1024;
    unsigned s = p[t] + p[t + 256] + p[t + 512] + p[t + 768];
    __shared__ unsigned red[256];
    red[t] = s;
    for (int off = 128; off > 0; off >>= 1) {
        __syncthreads();
        if (t < off) red[t] += red[t + off];
    }
    if (t == 0) csum[blockIdx.x] = red[0];
}

// ---------------- scan2: refine to exact 32-bit key, emit threshold floats --------------
__global__ void __launch_bounds__(BLK) scan2_kernel(unsigned* __restrict__ ws) {
    __shared__ unsigned part[256];
    __shared__ unsigned s_c, s_r;
    const unsigned* hist2 = ws + OFF_HIST2;
    const unsigned* csum = ws + OFF_CSUM;
    const unsigned* meta = ws + OFF_META;
    float* thr = (float*)(ws + OFF_THR);
    int t = threadIdx.x;
    int tgt = blockIdx.x;   // 0 = low threshold, 1 = high threshold
    unsigned b = meta[tgt * 2];
    unsigned R = meta[tgt * 2 + 1];

    const unsigned* cs = csum + tgt * 1024;
    unsigned v[4];
    unsigned sum = 0u;
#pragma unroll
    for (int i = 0; i < 4; i++) { v[i] = cs[t * 4 + i]; sum += v[i]; }
    part[t] = sum;
    __syncthreads();
    for (int off = 1; off < 256; off <<= 1) {
        unsigned a = (t >= off) ? part[t - off] : 0u;
        __syncthreads();
        part[t] += a;
        __syncthreads();
    }
    {
        unsigned incl = part[t], excl = incl - sum;
        if (excl < R && incl >= R) {
            unsigned cum = excl;
            for (int i = 0; i < 4; i++) {
                if (cum + v[i] >= R) { s_c = (unsigned)(t * 4 + i); s_r = R - cum; break; }
                cum += v[i];
            }
        }
    }
    __syncthreads();
    unsigned c = s_c;
    unsigned R2 = s_r;
    __syncthreads();

    const unsigned* hp = hist2 + (size_t)tgt * (1u << 20) + (size_t)c * 1024;
    unsigned w[4];
    unsigned sum2 = 0u;
#pragma unroll
    for (int i = 0; i < 4; i++) { w[i] = hp[t * 4 + i]; sum2 += w[i]; }
    part[t] = sum2;
    __syncthreads();
    for (int off = 1; off < 256; off <<= 1) {
        unsigned a = (t >= off) ? part[t - off] : 0u;
        __syncthreads();
        part[t] += a;
        __syncthreads();
    }
    {
        unsigned incl = part[t], excl = incl - sum2;
        if (excl < R2 && incl >= R2) {
            unsigned cum = excl;
            for (int i = 0; i < 4; i++) {
                if (cum + w[i] >= R2) {
                    unsigned j = (unsigned)(t * 4 + i);
                    unsigned key = (b << 20) | (c << 10) | j;
                    thr[tgt] = key2f(key);
                    break;
                }
                cum += w[i];
            }
        }
    }
}

// ---------------- fixup: rewrite ambiguous elements with exact-threshold masks ----------
__global__ void __launch_bounds__(BLK) fixup_kernel(const float* __restrict__ x,
                                                    const float* __restrict__ sl_,
                                                    const float* __restrict__ zl_,
                                                    const float* __restrict__ sh_,
                                                    const float* __restrict__ zh_,
                                                    float* __restrict__ out,
                                                    unsigned* __restrict__ ws,
                                                    unsigned side_cap) {
    const float* thr = (const float*)(ws + OFF_THR);
    const float lowT = thr[0];
    const float highT = thr[1];
    const unsigned oflow = __builtin_amdgcn_readfirstlane(ws[OFF_OFLOW]);
    const int stride = GRID * BLK;
    const int gtid = blockIdx.x * BLK + threadIdx.x;

    if (!oflow) {
        unsigned n = ws[OFF_COUNT];
        if (n > side_cap) n = side_cap;
        const uint2* side = (const uint2*)(ws + OFF_SIDE);
        for (unsigned i = gtid; i < n; i += stride) {
            uint2 e = side[i];
            unsigned idx = e.x;
            float xx = __uint_as_float(e.y);
            unsigned row = idx / COLS;
            bool m = (xx > lowT) && (xx < highT);
            out[idx] = qdq(xx, m, sl_[row], zl_[row], sh_[row], zh_[row]);
        }
    } else {
        // Fallback (never taken for this data): full repair of candidate-bucket elements.
        const unsigned b_lo = ws[OFF_META + 0];
        const unsigned b_hi = ws[OFF_META + 2];
        for (int j = gtid; j < NTOT; j += stride) {
            float xx = x[j];
            unsigned top = f2key(xx) >> 20;
            if (top == b_lo || top == b_hi) {
                unsigned row = (unsigned)j / COLS;
                bool m = (xx > lowT) && (xx < highT);
                out[j] = qdq(xx, m, sl_[row], zl_[row], sh_[row], zh_[row]);
            }
        }
    }
}

extern "C" void kernel_launch(void* const* d_in, const int* in_sizes, int n_in,
                              void* d_out, int out_size, void* d_ws, size_t ws_size,
                              hipStream_t stream) {
    const float* x  = (const float*)d_in[0];
    const float* sl = (const float*)d_in[1];
    const float* zl = (const float*)d_in[2];
    const float* sh = (const float*)d_in[3];
    const float* zh = (const float*)d_in[4];
    float* out = (float*)d_out;
    unsigned* ws = (unsigned*)d_ws;

    // side-list capacity from actual workspace size (uint2 entries)
    unsigned side_cap = 0;
    size_t fixed_bytes = (size_t)OFF_SIDE * 4;
    if (ws_size > fixed_bytes + 8) {
        size_t cap = (ws_size - fixed_bytes) / 8;
        side_cap = (cap > (size_t)NTOT) ? (unsigned)NTOT : (unsigned)cap;
    }

    hipMemsetAsync(d_ws, 0, (size_t)ZERO_WORDS * 4, stream);

    hist12_kernel<<<GRID, BLK, 0, stream>>>(x, ws);
    scan1_kernel<<<1, BLK, 0, stream>>>(ws);
    pass2_kernel<<<GRID, BLK, 0, stream>>>(x, sl, zl, sh, zh, out, ws, side_cap);
    chunksum_kernel<<<2048, BLK, 0, stream>>>(ws);
    scan2_kernel<<<2, BLK, 0, stream>>>(ws);
    fixup_kernel<<<GRID, BLK, 0, stream>>>(x, sl, zl, sh, zh, out, ws, side_cap);
}

// Round 4
// 499.461 us; speedup vs baseline: 4.7716x; 4.7716x over previous
//
#include <hip/hip_runtime.h>
#include <stdint.h>

// Problem constants (from reference)
#define ROWS 4096
#define COLS 11008
#define NTOT (ROWS * COLS)          // 45,088,768
#define NV4  (NTOT / 4)             // 11,272,192 (COLS % 4 == 0 -> float4 never crosses rows)
#define COLS4 (COLS / 4)            // 2752

// high_num = int(n*0.1); 1-indexed order-statistic ranks
#define HIGH_NUM 4508876u
#define RANK_LO  (HIGH_NUM / 2u)                   // 2,254,438
#define RANK_HI  ((unsigned)NTOT - HIGH_NUM / 2u)  // 42,834,330

#define BLK 256
#define GRID 2048
#define NTHR (GRID * BLK)
#define ITERS ((NV4 + NTHR - 1) / NTHR)   // 22 (uniform across all threads)

// ws layout (u32 words):
//  [0] side_count  [1] oflow  [2..3] pad
//  [4..11]  meta: (b_lo, r_lo, b_hi, r_hi)
//  [12..13] thr (2 floats)
//  [14..15] pad
//  [16 ..)          hist1[4096]
//  (.. +2048)       csum[2048]
//  (.. +2*2^20)     hist2[2*2^20]
//  then: side buffer of uint2 (idx, bits(x))
#define OFF_COUNT 0
#define OFF_OFLOW 1
#define OFF_META  4
#define OFF_THR   12
#define OFF_HIST1 16
#define OFF_CSUM  (OFF_HIST1 + 4096)
#define OFF_HIST2 (OFF_CSUM + 2048)
#define OFF_SIDE  (OFF_HIST2 + 2 * (1 << 20))   // even word offset -> uint2-aligned
#define ZERO_WORDS OFF_SIDE

__device__ __forceinline__ unsigned f2key(float f) {
    unsigned u = __float_as_uint(f);
    return (u & 0x80000000u) ? ~u : (u | 0x80000000u);
}
__device__ __forceinline__ float key2f(unsigned key) {
    unsigned u = (key & 0x80000000u) ? (key & 0x7fffffffu) : ~key;
    return __uint_as_float(u);
}

// Exact qdq, byte-identical to the passing R1/R3 math (IEEE div + nearest-even).
__device__ __forceinline__ float qdq(float xx, bool m, float sl, float zl, float sh, float zh) {
    float s  = m ? sl : sh;
    float z  = m ? zl : zh;
    float mq = m ? 1.0f : 255.0f;
    float q = rintf(xx / s) + z;
    q = fminf(fmaxf(q, 0.0f), mq);
    return s * (q - z);
}

// ---------------- Pass 1: 4096-bucket histogram of top 12 key bits (2 parity copies) ----
__global__ void __launch_bounds__(BLK) hist12_kernel(const float* __restrict__ x,
                                                     unsigned* __restrict__ ws) {
    __shared__ unsigned h[8192];
    for (int i = threadIdx.x; i < 8192; i += BLK) h[i] = 0u;
    __syncthreads();

    const float4* x4 = (const float4*)x;
    const int par = threadIdx.x & 1;
    for (int j = blockIdx.x * BLK + threadIdx.x; j < NV4; j += NTHR) {
        float4 v = x4[j];
        atomicAdd(&h[((f2key(v.x) >> 20) << 1) + par], 1u);
        atomicAdd(&h[((f2key(v.y) >> 20) << 1) + par], 1u);
        atomicAdd(&h[((f2key(v.z) >> 20) << 1) + par], 1u);
        atomicAdd(&h[((f2key(v.w) >> 20) << 1) + par], 1u);
    }
    __syncthreads();
    unsigned* hist1 = ws + OFF_HIST1;
    for (int i = threadIdx.x; i < 4096; i += BLK) {
        unsigned c = h[2 * i] + h[2 * i + 1];
        if (c) atomicAdd(&hist1[i], c);
    }
}

// ---------------- scan1: candidate top-12 bucket + residual rank for both targets -------
__global__ void __launch_bounds__(BLK) scan1_kernel(unsigned* __restrict__ ws) {
    __shared__ unsigned part[256];
    const unsigned* hist1 = ws + OFF_HIST1;
    unsigned* meta = ws + OFF_META;
    int t = threadIdx.x;
    unsigned v[16];
    unsigned sum = 0u;
#pragma unroll
    for (int i = 0; i < 16; i++) { v[i] = hist1[t * 16 + i]; sum += v[i]; }
    part[t] = sum;
    __syncthreads();
    for (int off = 1; off < 256; off <<= 1) {
        unsigned a = (t >= off) ? part[t - off] : 0u;
        __syncthreads();
        part[t] += a;
        __syncthreads();
    }
    unsigned incl = part[t];
    unsigned excl = incl - sum;
    unsigned ranks[2] = {RANK_LO, RANK_HI};
    for (int k = 0; k < 2; k++) {
        unsigned R = ranks[k];
        if (excl < R && incl >= R) {
            unsigned cum = excl;
            for (int i = 0; i < 16; i++) {
                if (cum + v[i] >= R) { meta[k * 2] = (unsigned)(t * 16 + i); meta[k * 2 + 1] = R - cum; break; }
                cum += v[i];
            }
        }
    }
}

// ---------------- Pass 2 (fused): hist20 + provisional quant + aggregated side list -----
__global__ void __launch_bounds__(BLK) pass2_kernel(const float* __restrict__ x,
                                                    const float* __restrict__ sl_,
                                                    const float* __restrict__ zl_,
                                                    const float* __restrict__ sh_,
                                                    const float* __restrict__ zh_,
                                                    float* __restrict__ out,
                                                    unsigned* __restrict__ ws,
                                                    unsigned side_cap) {
    __shared__ uint2 stage[2048];     // block staging for side entries (16 KB)
    __shared__ unsigned lcount;       // LDS fill counter
    __shared__ unsigned gbase;        // global reservation base for flushes

    const unsigned b_lo = __builtin_amdgcn_readfirstlane(ws[OFF_META + 0]);
    const unsigned b_hi = __builtin_amdgcn_readfirstlane(ws[OFF_META + 2]);
    unsigned* hist2 = ws + OFF_HIST2;
    uint2* side = (uint2*)(ws + OFF_SIDE);

    if (threadIdx.x == 0) lcount = 0u;
    __syncthreads();

    const float4* x4 = (const float4*)x;
    float4* o4 = (float4*)out;
    const int lane = threadIdx.x & 63;
    const int gtid = blockIdx.x * BLK + threadIdx.x;

    for (int it = 0; it < ITERS; ++it) {
        int j = gtid + it * NTHR;
        unsigned k = 0;
        uint2 loc[4];
        if (j < NV4) {
            int row = j / COLS4;
            float sl = sl_[row], zl = zl_[row];
            float sh = sh_[row], zh = zh_[row];
            float4 v = x4[j];
            float in[4] = {v.x, v.y, v.z, v.w};
            float r[4];
#pragma unroll
            for (int c = 0; c < 4; c++) {
                float xx = in[c];
                unsigned key = f2key(xx);
                unsigned top = key >> 20;
                if (top == b_lo) atomicAdd(&hist2[key & 0xFFFFFu], 1u);
                if (top == b_hi) atomicAdd(&hist2[(1u << 20) | (key & 0xFFFFFu)], 1u);
                // definite classification outside candidate buckets (key order == float order)
                bool m = (top > b_lo) && (top < b_hi);
                r[c] = qdq(xx, m, sl, zl, sh, zh);
                if ((top == b_lo) || (top == b_hi)) {
                    loc[k] = make_uint2((unsigned)j * 4u + (unsigned)c, __float_as_uint(xx));
                    k++;
                }
            }
            o4[j] = make_float4(r[0], r[1], r[2], r[3]);
        }

        // wave-aggregate the side-list reservation: one LDS atomic per wave
        unsigned pref = k;
#pragma unroll
        for (int off = 1; off < 64; off <<= 1) {
            unsigned nn = __shfl_up(pref, off, 64);
            if (lane >= off) pref += nn;
        }
        unsigned total = __shfl(pref, 63, 64);
        if (total) {
            unsigned wbase = 0;
            if (lane == 63) wbase = atomicAdd(&lcount, total);
            wbase = __shfl(wbase, 63, 64);
            unsigned e = wbase + pref - k;   // exclusive prefix within wave
            for (unsigned i = 0; i < k; i++) stage[e + i] = loc[i];
        }
        __syncthreads();
        if (lcount >= 1024u) {               // uniform; flush (one global atomic per flush)
            unsigned n = lcount;
            if (threadIdx.x == 0) gbase = atomicAdd(&ws[OFF_COUNT], n);
            __syncthreads();
            unsigned gb = gbase;
            for (unsigned i = threadIdx.x; i < n; i += BLK) {
                unsigned dst = gb + i;
                if (dst < side_cap) side[dst] = stage[i];
                else ws[OFF_OFLOW] = 1u;
            }
            __syncthreads();
            if (threadIdx.x == 0) lcount = 0u;
        }
        __syncthreads();
    }

    // final flush
    unsigned n = lcount;
    if (n) {
        if (threadIdx.x == 0) gbase = atomicAdd(&ws[OFF_COUNT], n);
        __syncthreads();
        unsigned gb = gbase;
        for (unsigned i = threadIdx.x; i < n; i += BLK) {
            unsigned dst = gb + i;
            if (dst < side_cap) side[dst] = stage[i];
            else ws[OFF_OFLOW] = 1u;
        }
    }
}

// ---------------- chunksum: 1024-entry chunk sums of hist2 (2048 chunks) ----------------
__global__ void __launch_bounds__(BLK) chunksum_kernel(unsigned* __restrict__ ws) {
    const unsigned* hist2 = ws + OFF_HIST2;
    unsigned* csum = ws + OFF_CSUM;
    int t = threadIdx.x;
    const unsigned* p = hist2 + (size_t)blockIdx.x * 1024;
    unsigned s = p[t] + p[t + 256] + p[t + 512] + p[t + 768];
    __shared__ unsigned red[256];
    red[t] = s;
    for (int off = 128; off > 0; off >>= 1) {
        __syncthreads();
        if (t < off) red[t] += red[t + off];
    }
    if (t == 0) csum[blockIdx.x] = red[0];
}

// ---------------- scan2: refine to exact 32-bit key, emit threshold floats --------------
__global__ void __launch_bounds__(BLK) scan2_kernel(unsigned* __restrict__ ws) {
    __shared__ unsigned part[256];
    __shared__ unsigned s_c, s_r;
    const unsigned* hist2 = ws + OFF_HIST2;
    const unsigned* csum = ws + OFF_CSUM;
    const unsigned* meta = ws + OFF_META;
    float* thr = (float*)(ws + OFF_THR);
    int t = threadIdx.x;
    int tgt = blockIdx.x;   // 0 = low threshold, 1 = high threshold
    unsigned b = meta[tgt * 2];
    unsigned R = meta[tgt * 2 + 1];

    const unsigned* cs = csum + tgt * 1024;
    unsigned v[4];
    unsigned sum = 0u;
#pragma unroll
    for (int i = 0; i < 4; i++) { v[i] = cs[t * 4 + i]; sum += v[i]; }
    part[t] = sum;
    __syncthreads();
    for (int off = 1; off < 256; off <<= 1) {
        unsigned a = (t >= off) ? part[t - off] : 0u;
        __syncthreads();
        part[t] += a;
        __syncthreads();
    }
    {
        unsigned incl = part[t], excl = incl - sum;
        if (excl < R && incl >= R) {
            unsigned cum = excl;
            for (int i = 0; i < 4; i++) {
                if (cum + v[i] >= R) { s_c = (unsigned)(t * 4 + i); s_r = R - cum; break; }
                cum += v[i];
            }
        }
    }
    __syncthreads();
    unsigned c = s_c;
    unsigned R2 = s_r;
    __syncthreads();

    const unsigned* hp = hist2 + (size_t)tgt * (1u << 20) + (size_t)c * 1024;
    unsigned w[4];
    unsigned sum2 = 0u;
#pragma unroll
    for (int i = 0; i < 4; i++) { w[i] = hp[t * 4 + i]; sum2 += w[i]; }
    part[t] = sum2;
    __syncthreads();
    for (int off = 1; off < 256; off <<= 1) {
        unsigned a = (t >= off) ? part[t - off] : 0u;
        __syncthreads();
        part[t] += a;
        __syncthreads();
    }
    {
        unsigned incl = part[t], excl = incl - sum2;
        if (excl < R2 && incl >= R2) {
            unsigned cum = excl;
            for (int i = 0; i < 4; i++) {
                if (cum + w[i] >= R2) {
                    unsigned j = (unsigned)(t * 4 + i);
                    unsigned key = (b << 20) | (c << 10) | j;
                    thr[tgt] = key2f(key);
                    break;
                }
                cum += w[i];
            }
        }
    }
}

// ---------------- fixup: rewrite ambiguous elements with exact-threshold masks ----------
__global__ void __launch_bounds__(BLK) fixup_kernel(const float* __restrict__ x,
                                                    const float* __restrict__ sl_,
                                                    const float* __restrict__ zl_,
                                                    const float* __restrict__ sh_,
                                                    const float* __restrict__ zh_,
                                                    float* __restrict__ out,
                                                    unsigned* __restrict__ ws,
                                                    unsigned side_cap) {
    const float* thr = (const float*)(ws + OFF_THR);
    const float lowT = thr[0];
    const float highT = thr[1];
    const unsigned oflow = __builtin_amdgcn_readfirstlane(ws[OFF_OFLOW]);
    const int gtid = blockIdx.x * BLK + threadIdx.x;

    if (!oflow) {
        unsigned n = ws[OFF_COUNT];
        if (n > side_cap) n = side_cap;
        const uint2* side = (const uint2*)(ws + OFF_SIDE);
        for (unsigned i = gtid; i < n; i += NTHR) {
            uint2 e = side[i];
            unsigned idx = e.x;
            float xx = __uint_as_float(e.y);
            unsigned row = idx / COLS;
            bool m = (xx > lowT) && (xx < highT);
            out[idx] = qdq(xx, m, sl_[row], zl_[row], sh_[row], zh_[row]);
        }
    } else {
        // Fallback (never taken for this data): full repair of candidate-bucket elements.
        const unsigned b_lo = ws[OFF_META + 0];
        const unsigned b_hi = ws[OFF_META + 2];
        for (int j = gtid; j < NTOT; j += NTHR) {
            float xx = x[j];
            unsigned top = f2key(xx) >> 20;
            if (top == b_lo || top == b_hi) {
                unsigned row = (unsigned)j / COLS;
                bool m = (xx > lowT) && (xx < highT);
                out[j] = qdq(xx, m, sl_[row], zl_[row], sh_[row], zh_[row]);
            }
        }
    }
}

extern "C" void kernel_launch(void* const* d_in, const int* in_sizes, int n_in,
                              void* d_out, int out_size, void* d_ws, size_t ws_size,
                              hipStream_t stream) {
    const float* x  = (const float*)d_in[0];
    const float* sl = (const float*)d_in[1];
    const float* zl = (const float*)d_in[2];
    const float* sh = (const float*)d_in[3];
    const float* zh = (const float*)d_in[4];
    float* out = (float*)d_out;
    unsigned* ws = (unsigned*)d_ws;

    // side-list capacity from actual workspace size (uint2 entries)
    unsigned side_cap = 0;
    size_t fixed_bytes = (size_t)OFF_SIDE * 4;
    if (ws_size > fixed_bytes + 8) {
        size_t cap = (ws_size - fixed_bytes) / 8;
        side_cap = (cap > (size_t)NTOT) ? (unsigned)NTOT : (unsigned)cap;
    }

    hipMemsetAsync(d_ws, 0, (size_t)ZERO_WORDS * 4, stream);

    hist12_kernel<<<GRID, BLK, 0, stream>>>(x, ws);
    scan1_kernel<<<1, BLK, 0, stream>>>(ws);
    pass2_kernel<<<GRID, BLK, 0, stream>>>(x, sl, zl, sh, zh, out, ws, side_cap);
    chunksum_kernel<<<2048, BLK, 0, stream>>>(ws);
    scan2_kernel<<<2, BLK, 0, stream>>>(ws);
    fixup_kernel<<<GRID, BLK, 0, stream>>>(x, sl, zl, sh, zh, out, ws, side_cap);
}

// Round 5
// 454.110 us; speedup vs baseline: 5.2481x; 1.0999x over previous
//
#include <hip/hip_runtime.h>
#include <stdint.h>

// Problem constants (from reference)
#define ROWS 4096
#define COLS 11008
#define NTOT (ROWS * COLS)          // 45,088,768
#define NV4  (NTOT / 4)             // 11,272,192 (COLS % 4 == 0 -> float4 never crosses rows)
#define COLS4 (COLS / 4)            // 2752

// high_num = int(n*0.1); 1-indexed order-statistic ranks
#define HIGH_NUM 4508876u
#define RANK_LO  (HIGH_NUM / 2u)                   // 2,254,438
#define RANK_HI  ((unsigned)NTOT - HIGH_NUM / 2u)  // 42,834,330

#define BLK 256
#define GRID 2048
#define NTHR (GRID * BLK)

// Sampling: 1024 blocks x 1024 contiguous float4 = 4,194,304 float samples (16 MB read)
#define SAMPLES 4194304ull
#define RS_LO ((unsigned)(((unsigned long long)RANK_LO * SAMPLES) / (unsigned long long)NTOT))
#define RS_HI ((unsigned)(((unsigned long long)RANK_HI * SAMPLES) / (unsigned long long)NTOT))

#define WSZ_KEYS (2u << 20)   // 2-bucket window, full 2^20 low-bit resolution per bucket

// ws layout (u32 words):
#define OFF_CLO   0                      // 64 slots: #elements with key < wstart_lo
#define OFF_CHI   64                     // 64 slots: #elements with key < wstart_hi
#define OFF_META  128                    // [0]=wstart_lo key, [1]=wstart_hi key
#define OFF_THR   132                    // 2 floats (exact thresholds)
#define OFF_H1S   256                    // 4096: sample 12-bit histogram
#define OFF_CSUM  (OFF_H1S + 4096)       // 4096 chunk sums (2048 per target)
#define OFF_WLO   (OFF_CSUM + 4096)      // 2^21 window hist (lo)
#define OFF_WHI   (OFF_WLO + WSZ_KEYS)   // 2^21 window hist (hi)
#define WS_WORDS  (OFF_WHI + WSZ_KEYS)   // ~16.8 MB total

__device__ __forceinline__ unsigned f2key(float f) {
    unsigned u = __float_as_uint(f);
    return (u & 0x80000000u) ? ~u : (u | 0x80000000u);
}
__device__ __forceinline__ float key2f(unsigned key) {
    unsigned u = (key & 0x80000000u) ? (key & 0x7fffffffu) : ~key;
    return __uint_as_float(u);
}

// Exact qdq, byte-identical to the passing R1/R4 math (IEEE div + nearest-even).
__device__ __forceinline__ float qdq(float xx, bool m, float sl, float zl, float sh, float zh) {
    float s  = m ? sl : sh;
    float z  = m ? zl : zh;
    float mq = m ? 1.0f : 255.0f;
    float q = rintf(xx / s) + z;
    q = fminf(fmaxf(q, 0.0f), mq);
    return s * (q - z);
}

// ---------- sample: 12-bit key histogram of 4M samples (contiguous chunks) ----------
__global__ void __launch_bounds__(BLK) sample_kernel(const float* __restrict__ x,
                                                     unsigned* __restrict__ ws) {
    __shared__ unsigned h[8192];      // 2 parity copies
    for (int i = threadIdx.x; i < 8192; i += BLK) h[i] = 0u;
    __syncthreads();

    const float4* x4 = (const float4*)x;
    const unsigned base = blockIdx.x * 11008u;   // NV4/1024 = 11008; base+1023 < NV4
    const int par = threadIdx.x & 1;
#pragma unroll
    for (int i = 0; i < 4; i++) {
        float4 v = x4[base + threadIdx.x + 256 * i];
        atomicAdd(&h[((f2key(v.x) >> 20) << 1) + par], 1u);
        atomicAdd(&h[((f2key(v.y) >> 20) << 1) + par], 1u);
        atomicAdd(&h[((f2key(v.z) >> 20) << 1) + par], 1u);
        atomicAdd(&h[((f2key(v.w) >> 20) << 1) + par], 1u);
    }
    __syncthreads();
    unsigned* hist = ws + OFF_H1S;
    for (int i = threadIdx.x; i < 4096; i += BLK) {
        unsigned c = h[2 * i] + h[2 * i + 1];
        if (c) atomicAdd(&hist[i], c);
    }
}

// ---------- scan_sample: pick 2-bucket key windows bracketing each threshold ----------
__global__ void __launch_bounds__(BLK) scan_sample_kernel(unsigned* __restrict__ ws) {
    __shared__ unsigned part[256];
    const unsigned* hist = ws + OFF_H1S;
    unsigned* meta = ws + OFF_META;
    int t = threadIdx.x;
    unsigned v[16];
    unsigned sum = 0u;
#pragma unroll
    for (int i = 0; i < 16; i++) { v[i] = hist[t * 16 + i]; sum += v[i]; }
    part[t] = sum;
    __syncthreads();
    for (int off = 1; off < 256; off <<= 1) {
        unsigned a = (t >= off) ? part[t - off] : 0u;
        __syncthreads();
        part[t] += a;
        __syncthreads();
    }
    unsigned incl = part[t];
    unsigned excl = incl - sum;
    unsigned ranks[2] = {RS_LO, RS_HI};
    for (int k = 0; k < 2; k++) {
        unsigned Rs = ranks[k];
        if (excl < Rs && incl >= Rs) {
            unsigned cum = excl;
            for (int i = 0; i < 16; i++) {
                if (cum + v[i] >= Rs) {
                    unsigned b = (unsigned)(t * 16 + i);
                    unsigned rel = Rs - cum;           // 1..v[i]
                    // adaptive 2-bucket window: include lower or upper neighbor
                    unsigned wb = (2u * rel <= v[i]) ? (b > 0 ? b - 1 : 0) : b;
                    if (wb > 4094u) wb = 4094u;
                    meta[k] = wb << 20;                // window start KEY
                    break;
                }
                cum += v[i];
            }
        }
    }
}

// ---------- passA: exact below-window counts + in-window fine histograms ----------
__global__ void __launch_bounds__(BLK) passA_kernel(const float* __restrict__ x,
                                                    unsigned* __restrict__ ws) {
    const unsigned wlo = __builtin_amdgcn_readfirstlane(ws[OFF_META + 0]);
    const unsigned whi = __builtin_amdgcn_readfirstlane(ws[OFF_META + 1]);
    unsigned* hLo = ws + OFF_WLO;
    unsigned* hHi = ws + OFF_WHI;

    const float4* x4 = (const float4*)x;
    unsigned cLo = 0u, cHi = 0u;
    for (int j = blockIdx.x * BLK + threadIdx.x; j < NV4; j += NTHR) {
        float4 v = x4[j];
        float f[4] = {v.x, v.y, v.z, v.w};
#pragma unroll
        for (int c = 0; c < 4; c++) {
            unsigned key = f2key(f[c]);
            cLo += (key < wlo) ? 1u : 0u;
            cHi += (key < whi) ? 1u : 0u;
            unsigned dlo = key - wlo;   // wraps huge when key < wlo
            if (dlo < WSZ_KEYS) atomicAdd(&hLo[dlo], 1u);
            unsigned dhi = key - whi;
            if (dhi < WSZ_KEYS) atomicAdd(&hHi[dhi], 1u);
        }
    }

    __shared__ unsigned red[256];
    red[threadIdx.x] = cLo;
    for (int off = 128; off > 0; off >>= 1) {
        __syncthreads();
        if (threadIdx.x < off) red[threadIdx.x] += red[threadIdx.x + off];
    }
    if (threadIdx.x == 0) atomicAdd(&ws[OFF_CLO + (blockIdx.x & 63)], red[0]);
    __syncthreads();
    red[threadIdx.x] = cHi;
    for (int off = 128; off > 0; off >>= 1) {
        __syncthreads();
        if (threadIdx.x < off) red[threadIdx.x] += red[threadIdx.x + off];
    }
    if (threadIdx.x == 0) atomicAdd(&ws[OFF_CHI + (blockIdx.x & 63)], red[0]);
}

// ---------- chunksum: 1024-entry chunk sums over both window hists (4096 chunks) --------
__global__ void __launch_bounds__(BLK) chunksum_kernel(unsigned* __restrict__ ws) {
    const unsigned* p = ws + OFF_WLO + (size_t)blockIdx.x * 1024;
    int t = threadIdx.x;
    unsigned s = p[t] + p[t + 256] + p[t + 512] + p[t + 768];
    __shared__ unsigned red[256];
    red[t] = s;
    for (int off = 128; off > 0; off >>= 1) {
        __syncthreads();
        if (t < off) red[t] += red[t + off];
    }
    if (t == 0) ws[OFF_CSUM + blockIdx.x] = red[0];
}

// ---------- scanB: below-count + window prefix -> exact 32-bit key -> threshold ---------
__global__ void __launch_bounds__(BLK) scanB_kernel(unsigned* __restrict__ ws) {
    __shared__ unsigned part[256];
    __shared__ unsigned s_C, s_c, s_r;
    const int t = threadIdx.x;
    const int tgt = blockIdx.x;   // 0 = low, 1 = high
    float* thr = (float*)(ws + OFF_THR);

    // C = sum of 64 count slots
    part[t] = (t < 64) ? ws[(tgt ? OFF_CHI : OFF_CLO) + t] : 0u;
    for (int off = 128; off > 0; off >>= 1) {
        __syncthreads();
        if (t < off) part[t] += part[t + off];
    }
    if (t == 0) s_C = part[0];
    __syncthreads();
    const unsigned RANK = tgt ? RANK_HI : RANK_LO;
    const unsigned R = RANK - s_C;   // residual rank inside window (window brackets threshold)
    __syncthreads();

    // Phase 1: scan this target's 2048 chunk sums
    const unsigned* cs = ws + OFF_CSUM + tgt * 2048;
    unsigned v[8];
    unsigned sum = 0u;
#pragma unroll
    for (int i = 0; i < 8; i++) { v[i] = cs[t * 8 + i]; sum += v[i]; }
    part[t] = sum;
    __syncthreads();
    for (int off = 1; off < 256; off <<= 1) {
        unsigned a = (t >= off) ? part[t - off] : 0u;
        __syncthreads();
        part[t] += a;
        __syncthreads();
    }
    {
        unsigned incl = part[t], excl = incl - sum;
        if (excl < R && incl >= R) {
            unsigned cum = excl;
            for (int i = 0; i < 8; i++) {
                if (cum + v[i] >= R) { s_c = (unsigned)(t * 8 + i); s_r = R - cum; break; }
                cum += v[i];
            }
        }
    }
    __syncthreads();
    const unsigned c  = s_c;
    const unsigned R2 = s_r;
    __syncthreads();

    // Phase 2: scan the chosen 1024-entry chunk
    const unsigned* hp = ws + OFF_WLO + (size_t)tgt * WSZ_KEYS + (size_t)c * 1024;
    unsigned w[4];
    unsigned sum2 = 0u;
#pragma unroll
    for (int i = 0; i < 4; i++) { w[i] = hp[t * 4 + i]; sum2 += w[i]; }
    part[t] = sum2;
    __syncthreads();
    for (int off = 1; off < 256; off <<= 1) {
        unsigned a = (t >= off) ? part[t - off] : 0u;
        __syncthreads();
        part[t] += a;
        __syncthreads();
    }
    {
        unsigned incl = part[t], excl = incl - sum2;
        if (excl < R2 && incl >= R2) {
            unsigned cum = excl;
            for (int i = 0; i < 4; i++) {
                if (cum + w[i] >= R2) {
                    unsigned key = ws[OFF_META + tgt] + (c * 1024u + (unsigned)(t * 4 + i));
                    thr[tgt] = key2f(key);
                    break;
                }
                cum += w[i];
            }
        }
    }
}

// ---------- quant: pure streaming dual qdq (no atomics, no side lists) ----------
__global__ void __launch_bounds__(BLK) quant_kernel(const float* __restrict__ x,
                                                    const float* __restrict__ sl_,
                                                    const float* __restrict__ zl_,
                                                    const float* __restrict__ sh_,
                                                    const float* __restrict__ zh_,
                                                    const unsigned* __restrict__ ws,
                                                    float* __restrict__ out) {
    const float lowT  = __uint_as_float(__builtin_amdgcn_readfirstlane(ws[OFF_THR + 0]));
    const float highT = __uint_as_float(__builtin_amdgcn_readfirstlane(ws[OFF_THR + 1]));
    const float4* x4 = (const float4*)x;
    float4* o4 = (float4*)out;
    for (int j = blockIdx.x * BLK + threadIdx.x; j < NV4; j += NTHR) {
        int row = j / COLS4;
        float sl = sl_[row], zl = zl_[row];
        float sh = sh_[row], zh = zh_[row];
        float4 v = x4[j];
        float in[4] = {v.x, v.y, v.z, v.w};
        float r[4];
#pragma unroll
        for (int c = 0; c < 4; c++) {
            float xx = in[c];
            bool m = (xx > lowT) && (xx < highT);   // bulk -> 1-bit path
            r[c] = qdq(xx, m, sl, zl, sh, zh);
        }
        o4[j] = make_float4(r[0], r[1], r[2], r[3]);
    }
}

extern "C" void kernel_launch(void* const* d_in, const int* in_sizes, int n_in,
                              void* d_out, int out_size, void* d_ws, size_t ws_size,
                              hipStream_t stream) {
    const float* x  = (const float*)d_in[0];
    const float* sl = (const float*)d_in[1];
    const float* zl = (const float*)d_in[2];
    const float* sh = (const float*)d_in[3];
    const float* zh = (const float*)d_in[4];
    float* out = (float*)d_out;
    unsigned* ws = (unsigned*)d_ws;

    hipMemsetAsync(d_ws, 0, (size_t)WS_WORDS * 4, stream);   // ~16.8 MB

    sample_kernel<<<1024, BLK, 0, stream>>>(x, ws);
    scan_sample_kernel<<<1, BLK, 0, stream>>>(ws);
    passA_kernel<<<GRID, BLK, 0, stream>>>(x, ws);
    chunksum_kernel<<<4096, BLK, 0, stream>>>(ws);
    scanB_kernel<<<2, BLK, 0, stream>>>(ws);
    quant_kernel<<<GRID, BLK, 0, stream>>>(x, sl, zl, sh, zh, ws, out);
}

// Round 7
// 443.811 us; speedup vs baseline: 5.3699x; 1.0232x over previous
//
#include <hip/hip_runtime.h>
#include <stdint.h>

// Problem constants (from reference)
#define ROWS 4096
#define COLS 11008
#define NTOT (ROWS * COLS)          // 45,088,768
#define NV4  (NTOT / 4)             // 11,272,192 (COLS % 4 == 0 -> float4 never crosses rows)
#define COLS4 (COLS / 4)            // 2752

// high_num = int(n*0.1); 1-indexed order-statistic ranks
#define HIGH_NUM 4508876u
#define RANK_LO  (HIGH_NUM / 2u)                   // 2,254,438
#define RANK_HI  ((unsigned)NTOT - HIGH_NUM / 2u)  // 42,834,330

#define BLK 256
#define GRID 2048
#define NTHR (GRID * BLK)
#define NTILES 11008                 // NV4 / 1024 exactly (tile = 1024 float4)

// Sampling: 1024 blocks x 1024 contiguous float4 = 4,194,304 float samples (16 MB read)
#define SAMPLES 4194304ull
#define RS_LO ((unsigned)(((unsigned long long)RANK_LO * SAMPLES) / (unsigned long long)NTOT))
#define RS_HI ((unsigned)(((unsigned long long)RANK_HI * SAMPLES) / (unsigned long long)NTOT))

#define WSZ_KEYS (2u << 20)   // 2-bucket window, full 2^20 low-bit resolution per bucket

// ws layout (u32 words):
#define OFF_CLO   0                      // 64 slots: #elements with key < wstart_lo
#define OFF_CHI   64                     // 64 slots: #elements with key < wstart_hi
#define OFF_META  128                    // [0]=wstart_lo key, [1]=wstart_hi key
#define OFF_THR   132                    // 2 floats (exact thresholds)
#define OFF_H1S   256                    // 4096: sample 12-bit histogram
#define OFF_CSUM  (OFF_H1S + 4096)       // 4096 chunk sums (2048 per target)
#define OFF_WLO   (OFF_CSUM + 4096)      // 2^21 window hist (lo)
#define OFF_WHI   (OFF_WLO + WSZ_KEYS)   // 2^21 window hist (hi)
#define WS_WORDS  (OFF_WHI + WSZ_KEYS)   // ~16.8 MB total

typedef float vfloat4 __attribute__((ext_vector_type(4)));   // NT-store-compatible

__device__ __forceinline__ unsigned f2key(float f) {
    unsigned u = __float_as_uint(f);
    return (u & 0x80000000u) ? ~u : (u | 0x80000000u);
}
__device__ __forceinline__ float key2f(unsigned key) {
    unsigned u = (key & 0x80000000u) ? (key & 0x7fffffffu) : ~key;
    return __uint_as_float(u);
}

// Exact qdq, byte-identical to the passing R1..R5 math (IEEE div + nearest-even).
__device__ __forceinline__ float qdq(float xx, bool m, float sl, float zl, float sh, float zh) {
    float s  = m ? sl : sh;
    float z  = m ? zl : zh;
    float mq = m ? 1.0f : 255.0f;
    float q = rintf(xx / s) + z;
    q = fminf(fmaxf(q, 0.0f), mq);
    return s * (q - z);
}

// ---------- sample: 12-bit key histogram of 4M samples (contiguous chunks) ----------
__global__ void __launch_bounds__(BLK) sample_kernel(const float* __restrict__ x,
                                                     unsigned* __restrict__ ws) {
    __shared__ unsigned h[8192];      // 2 parity copies
    for (int i = threadIdx.x; i < 8192; i += BLK) h[i] = 0u;
    __syncthreads();

    const float4* x4 = (const float4*)x;
    const unsigned base = blockIdx.x * 11008u;   // NV4/1024 = 11008; base+1023 < NV4
    const int par = threadIdx.x & 1;
#pragma unroll
    for (int i = 0; i < 4; i++) {
        float4 v = x4[base + threadIdx.x + 256 * i];
        atomicAdd(&h[((f2key(v.x) >> 20) << 1) + par], 1u);
        atomicAdd(&h[((f2key(v.y) >> 20) << 1) + par], 1u);
        atomicAdd(&h[((f2key(v.z) >> 20) << 1) + par], 1u);
        atomicAdd(&h[((f2key(v.w) >> 20) << 1) + par], 1u);
    }
    __syncthreads();
    unsigned* hist = ws + OFF_H1S;
    for (int i = threadIdx.x; i < 4096; i += BLK) {
        unsigned c = h[2 * i] + h[2 * i + 1];
        if (c) atomicAdd(&hist[i], c);
    }
}

// ---------- scan_sample: pick 2-bucket key windows bracketing each threshold ----------
__global__ void __launch_bounds__(BLK) scan_sample_kernel(unsigned* __restrict__ ws) {
    __shared__ unsigned part[256];
    const unsigned* hist = ws + OFF_H1S;
    unsigned* meta = ws + OFF_META;
    int t = threadIdx.x;
    unsigned v[16];
    unsigned sum = 0u;
#pragma unroll
    for (int i = 0; i < 16; i++) { v[i] = hist[t * 16 + i]; sum += v[i]; }
    part[t] = sum;
    __syncthreads();
    for (int off = 1; off < 256; off <<= 1) {
        unsigned a = (t >= off) ? part[t - off] : 0u;
        __syncthreads();
        part[t] += a;
        __syncthreads();
    }
    unsigned incl = part[t];
    unsigned excl = incl - sum;
    unsigned ranks[2] = {RS_LO, RS_HI};
    for (int k = 0; k < 2; k++) {
        unsigned Rs = ranks[k];
        if (excl < Rs && incl >= Rs) {
            unsigned cum = excl;
            for (int i = 0; i < 16; i++) {
                if (cum + v[i] >= Rs) {
                    unsigned b = (unsigned)(t * 16 + i);
                    unsigned rel = Rs - cum;           // 1..v[i]
                    // adaptive 2-bucket window: include lower or upper neighbor
                    unsigned wb = (2u * rel <= v[i]) ? (b > 0 ? b - 1 : 0) : b;
                    if (wb > 4094u) wb = 4094u;
                    meta[k] = wb << 20;                // window start KEY
                    break;
                }
                cum += v[i];
            }
        }
    }
}

// ---------- passA: exact below-window counts + in-window fine histograms (4x ILP) -------
__device__ __forceinline__ void passA_elem(float f, unsigned wlo, unsigned whi,
                                           unsigned& cLo, unsigned& cHi,
                                           unsigned* hLo, unsigned* hHi) {
    unsigned key = f2key(f);
    cLo += (key < wlo) ? 1u : 0u;
    cHi += (key < whi) ? 1u : 0u;
    unsigned dlo = key - wlo;          // wraps huge when key < wlo
    if (dlo < WSZ_KEYS) atomicAdd(&hLo[dlo], 1u);
    unsigned dhi = key - whi;
    if (dhi < WSZ_KEYS) atomicAdd(&hHi[dhi], 1u);
}

__global__ void __launch_bounds__(BLK) passA_kernel(const float* __restrict__ x,
                                                    unsigned* __restrict__ ws) {
    const unsigned wlo = __builtin_amdgcn_readfirstlane(ws[OFF_META + 0]);
    const unsigned whi = __builtin_amdgcn_readfirstlane(ws[OFF_META + 1]);
    unsigned* hLo = ws + OFF_WLO;
    unsigned* hHi = ws + OFF_WHI;

    const float4* x4 = (const float4*)x;
    unsigned cLo = 0u, cHi = 0u;

    for (unsigned tile = blockIdx.x; tile < NTILES; tile += gridDim.x) {
        const float4* p = x4 + (size_t)tile * 1024u + threadIdx.x;
        // 4 independent coalesced loads in flight before any use
        float4 a = p[0];
        float4 b = p[256];
        float4 c = p[512];
        float4 d = p[768];
        passA_elem(a.x, wlo, whi, cLo, cHi, hLo, hHi);
        passA_elem(a.y, wlo, whi, cLo, cHi, hLo, hHi);
        passA_elem(a.z, wlo, whi, cLo, cHi, hLo, hHi);
        passA_elem(a.w, wlo, whi, cLo, cHi, hLo, hHi);
        passA_elem(b.x, wlo, whi, cLo, cHi, hLo, hHi);
        passA_elem(b.y, wlo, whi, cLo, cHi, hLo, hHi);
        passA_elem(b.z, wlo, whi, cLo, cHi, hLo, hHi);
        passA_elem(b.w, wlo, whi, cLo, cHi, hLo, hHi);
        passA_elem(c.x, wlo, whi, cLo, cHi, hLo, hHi);
        passA_elem(c.y, wlo, whi, cLo, cHi, hLo, hHi);
        passA_elem(c.z, wlo, whi, cLo, cHi, hLo, hHi);
        passA_elem(c.w, wlo, whi, cLo, cHi, hLo, hHi);
        passA_elem(d.x, wlo, whi, cLo, cHi, hLo, hHi);
        passA_elem(d.y, wlo, whi, cLo, cHi, hLo, hHi);
        passA_elem(d.z, wlo, whi, cLo, cHi, hLo, hHi);
        passA_elem(d.w, wlo, whi, cLo, cHi, hLo, hHi);
    }

    __shared__ unsigned red[256];
    red[threadIdx.x] = cLo;
    for (int off = 128; off > 0; off >>= 1) {
        __syncthreads();
        if (threadIdx.x < off) red[threadIdx.x] += red[threadIdx.x + off];
    }
    if (threadIdx.x == 0) atomicAdd(&ws[OFF_CLO + (blockIdx.x & 63)], red[0]);
    __syncthreads();
    red[threadIdx.x] = cHi;
    for (int off = 128; off > 0; off >>= 1) {
        __syncthreads();
        if (threadIdx.x < off) red[threadIdx.x] += red[threadIdx.x + off];
    }
    if (threadIdx.x == 0) atomicAdd(&ws[OFF_CHI + (blockIdx.x & 63)], red[0]);
}

// ---------- chunksum: 1024-entry chunk sums over both window hists (4096 chunks) --------
__global__ void __launch_bounds__(BLK) chunksum_kernel(unsigned* __restrict__ ws) {
    const unsigned* p = ws + OFF_WLO + (size_t)blockIdx.x * 1024;
    int t = threadIdx.x;
    unsigned s = p[t] + p[t + 256] + p[t + 512] + p[t + 768];
    __shared__ unsigned red[256];
    red[t] = s;
    for (int off = 128; off > 0; off >>= 1) {
        __syncthreads();
        if (t < off) red[t] += red[t + off];
    }
    if (t == 0) ws[OFF_CSUM + blockIdx.x] = red[0];
}

// ---------- scanB: below-count + window prefix -> exact 32-bit key -> threshold ---------
__global__ void __launch_bounds__(BLK) scanB_kernel(unsigned* __restrict__ ws) {
    __shared__ unsigned part[256];
    __shared__ unsigned s_C, s_c, s_r;
    const int t = threadIdx.x;
    const int tgt = blockIdx.x;   // 0 = low, 1 = high
    float* thr = (float*)(ws + OFF_THR);

    // C = sum of 64 count slots
    part[t] = (t < 64) ? ws[(tgt ? OFF_CHI : OFF_CLO) + t] : 0u;
    for (int off = 128; off > 0; off >>= 1) {
        __syncthreads();
        if (t < off) part[t] += part[t + off];
    }
    if (t == 0) s_C = part[0];
    __syncthreads();
    const unsigned RANK = tgt ? RANK_HI : RANK_LO;
    const unsigned R = RANK - s_C;   // residual rank inside window (window brackets threshold)
    __syncthreads();

    // Phase 1: scan this target's 2048 chunk sums
    const unsigned* cs = ws + OFF_CSUM + tgt * 2048;
    unsigned v[8];
    unsigned sum = 0u;
#pragma unroll
    for (int i = 0; i < 8; i++) { v[i] = cs[t * 8 + i]; sum += v[i]; }
    part[t] = sum;
    __syncthreads();
    for (int off = 1; off < 256; off <<= 1) {
        unsigned a = (t >= off) ? part[t - off] : 0u;
        __syncthreads();
        part[t] += a;
        __syncthreads();
    }
    {
        unsigned incl = part[t], excl = incl - sum;
        if (excl < R && incl >= R) {
            unsigned cum = excl;
            for (int i = 0; i < 8; i++) {
                if (cum + v[i] >= R) { s_c = (unsigned)(t * 8 + i); s_r = R - cum; break; }
                cum += v[i];
            }
        }
    }
    __syncthreads();
    const unsigned c  = s_c;
    const unsigned R2 = s_r;
    __syncthreads();

    // Phase 2: scan the chosen 1024-entry chunk
    const unsigned* hp = ws + OFF_WLO + (size_t)tgt * WSZ_KEYS + (size_t)c * 1024;
    unsigned w[4];
    unsigned sum2 = 0u;
#pragma unroll
    for (int i = 0; i < 4; i++) { w[i] = hp[t * 4 + i]; sum2 += w[i]; }
    part[t] = sum2;
    __syncthreads();
    for (int off = 1; off < 256; off <<= 1) {
        unsigned a = (t >= off) ? part[t - off] : 0u;
        __syncthreads();
        part[t] += a;
        __syncthreads();
    }
    {
        unsigned incl = part[t], excl = incl - sum2;
        if (excl < R2 && incl >= R2) {
            unsigned cum = excl;
            for (int i = 0; i < 4; i++) {
                if (cum + w[i] >= R2) {
                    unsigned key = ws[OFF_META + tgt] + (c * 1024u + (unsigned)(t * 4 + i));
                    thr[tgt] = key2f(key);
                    break;
                }
                cum += w[i];
            }
        }
    }
}

// ---------- quant: pure streaming dual qdq, 4x ILP, nontemporal stores ----------
__global__ void __launch_bounds__(BLK) quant_kernel(const float* __restrict__ x,
                                                    const float* __restrict__ sl_,
                                                    const float* __restrict__ zl_,
                                                    const float* __restrict__ sh_,
                                                    const float* __restrict__ zh_,
                                                    const unsigned* __restrict__ ws,
                                                    float* __restrict__ out) {
    const float lowT  = __uint_as_float(__builtin_amdgcn_readfirstlane(ws[OFF_THR + 0]));
    const float highT = __uint_as_float(__builtin_amdgcn_readfirstlane(ws[OFF_THR + 1]));
    const float4* x4 = (const float4*)x;
    vfloat4* o4 = (vfloat4*)out;

    for (unsigned tile = blockIdx.x; tile < NTILES; tile += gridDim.x) {
        const size_t base = (size_t)tile * 1024u + threadIdx.x;
        float4 vv[4];
        vv[0] = x4[base];
        vv[1] = x4[base + 256];
        vv[2] = x4[base + 512];
        vv[3] = x4[base + 768];
#pragma unroll
        for (int u = 0; u < 4; u++) {
            unsigned j = (unsigned)(base + 256u * u);
            unsigned row = j / COLS4;
            float sl = sl_[row], zl = zl_[row];
            float sh = sh_[row], zh = zh_[row];
            float in[4] = {vv[u].x, vv[u].y, vv[u].z, vv[u].w};
            float r[4];
#pragma unroll
            for (int c = 0; c < 4; c++) {
                float xx = in[c];
                bool m = (xx > lowT) && (xx < highT);   // bulk -> 1-bit path
                r[c] = qdq(xx, m, sl, zl, sh, zh);
            }
            vfloat4 rv = {r[0], r[1], r[2], r[3]};
            __builtin_nontemporal_store(rv, &o4[j]);
        }
    }
}

extern "C" void kernel_launch(void* const* d_in, const int* in_sizes, int n_in,
                              void* d_out, int out_size, void* d_ws, size_t ws_size,
                              hipStream_t stream) {
    const float* x  = (const float*)d_in[0];
    const float* sl = (const float*)d_in[1];
    const float* zl = (const float*)d_in[2];
    const float* sh = (const float*)d_in[3];
    const float* zh = (const float*)d_in[4];
    float* out = (float*)d_out;
    unsigned* ws = (unsigned*)d_ws;

    (void)hipMemsetAsync(d_ws, 0, (size_t)WS_WORDS * 4, stream);   // ~16.8 MB

    sample_kernel<<<1024, BLK, 0, stream>>>(x, ws);
    scan_sample_kernel<<<1, BLK, 0, stream>>>(ws);
    passA_kernel<<<GRID, BLK, 0, stream>>>(x, ws);
    chunksum_kernel<<<4096, BLK, 0, stream>>>(ws);
    scanB_kernel<<<2, BLK, 0, stream>>>(ws);
    quant_kernel<<<GRID, BLK, 0, stream>>>(x, sl, zl, sh, zh, ws, out);
}

// Round 8
// 391.943 us; speedup vs baseline: 6.0805x; 1.1323x over previous
//
#include <hip/hip_runtime.h>
#include <stdint.h>

// Problem constants (from reference)
#define ROWS 4096
#define COLS 11008
#define NTOT (ROWS * COLS)          // 45,088,768
#define NV4  (NTOT / 4)             // 11,272,192 (COLS % 4 == 0)
#define COLS4 (COLS / 4)            // 2752

// high_num = int(n*0.1); 1-indexed order-statistic ranks
#define HIGH_NUM 4508876u
#define RANK_LO  (HIGH_NUM / 2u)                   // 2,254,438
#define RANK_HI  ((unsigned)NTOT - HIGH_NUM / 2u)  // 42,834,330

#define BLK 256
#define GRID 2048
#define NTILES 11008                 // NV4 / 1024 (tile = 1024 float4)

// Sampling: 1024 blocks x 1024 contiguous float4 = 4,194,304 samples (16 MB)
#define SAMPLES 4194304ull
#define RS_LO ((unsigned)(((unsigned long long)RANK_LO * SAMPLES) / (unsigned long long)NTOT))
#define RS_HI ((unsigned)(((unsigned long long)RANK_HI * SAMPLES) / (unsigned long long)NTOT))
#define M_S 4500u                    // +/-10 sigma sample-rank margin

#define FSPAN (2u << 20)             // coarse window span: 2 x 12-bit buckets (keys)
#define FBINS (1u << 19)             // fine sample hist: 4-key bins over FSPAN
#define WMAX  (1u << 19)             // passA element hist: full-key-res window cap

// ws layout (u32 words), total ~8.4 MB (<= proven-available 16.8 MB)
#define OFF_CLO   0                       // 64 slots: exact #elems key < kA_lo
#define OFF_CHI   64                      // 64 slots: exact #elems key < kA_hi
#define OFF_META  128  // [0]=wstart_lo [1]=wstart_hi [2]=kA_lo [3]=width_lo
                       // [4]=kA_hi [5]=width_hi [6]=Cs_lo [7]=Cs_hi
#define OFF_THR   144                     // 2 floats (exact thresholds)
#define OFF_H1S   256                     // 4096 coarse sample hist
#define OFF_FCS   (OFF_H1S + 4096)        // 1024 fine-sample chunk sums (512/target)
#define OFF_WCS   (OFF_FCS + 1024)        // 1024 passA chunk sums (512/target)
#define OFF_FLO   8192                    // 2^19 fine sample hist (lo)
#define OFF_FHI   (OFF_FLO + FBINS)       // 2^19 fine sample hist (hi)
#define OFF_WLO   (OFF_FHI + FBINS)       // 2^19 passA element hist (lo)
#define OFF_WHI   (OFF_WLO + WMAX)        // 2^19 passA element hist (hi)
#define WS_WORDS  (OFF_WHI + WMAX)

typedef float vfloat4 __attribute__((ext_vector_type(4)));

__device__ __forceinline__ unsigned f2key(float f) {
    unsigned u = __float_as_uint(f);
    return (u & 0x80000000u) ? ~u : (u | 0x80000000u);
}
__device__ __forceinline__ float key2f(unsigned key) {
    unsigned u = (key & 0x80000000u) ? (key & 0x7fffffffu) : ~key;
    return __uint_as_float(u);
}
// Exact qdq (IEEE div + nearest-even) — byte-identical to all passing rounds.
__device__ __forceinline__ float qdq(float xx, bool m, float sl, float zl, float sh, float zh) {
    float s  = m ? sl : sh;
    float z  = m ? zl : zh;
    float mq = m ? 1.0f : 255.0f;
    float q = rintf(xx / s) + z;
    q = fminf(fmaxf(q, 0.0f), mq);
    return s * (q - z);
}

// ---------- sample: coarse 12-bit key histogram of 4M samples ----------
__global__ void __launch_bounds__(BLK) sample_kernel(const float* __restrict__ x,
                                                     unsigned* __restrict__ ws) {
    __shared__ unsigned h[8192];
    for (int i = threadIdx.x; i < 8192; i += BLK) h[i] = 0u;
    __syncthreads();
    const float4* x4 = (const float4*)x;
    const unsigned base = blockIdx.x * 11008u;
    const int par = threadIdx.x & 1;
#pragma unroll
    for (int i = 0; i < 4; i++) {
        float4 v = x4[base + threadIdx.x + 256 * i];
        atomicAdd(&h[((f2key(v.x) >> 20) << 1) + par], 1u);
        atomicAdd(&h[((f2key(v.y) >> 20) << 1) + par], 1u);
        atomicAdd(&h[((f2key(v.z) >> 20) << 1) + par], 1u);
        atomicAdd(&h[((f2key(v.w) >> 20) << 1) + par], 1u);
    }
    __syncthreads();
    unsigned* hist = ws + OFF_H1S;
    for (int i = threadIdx.x; i < 4096; i += BLK) {
        unsigned c = h[2 * i] + h[2 * i + 1];
        if (c) atomicAdd(&hist[i], c);
    }
}

// ---------- scan_sample: coarse 2-bucket windows + below-window sample counts ----------
__global__ void __launch_bounds__(BLK) scan_sample_kernel(unsigned* __restrict__ ws) {
    __shared__ unsigned part[256];
    const unsigned* hist = ws + OFF_H1S;
    unsigned* meta = ws + OFF_META;
    int t = threadIdx.x;
    unsigned v[16];
    unsigned sum = 0u;
#pragma unroll
    for (int i = 0; i < 16; i++) { v[i] = hist[t * 16 + i]; sum += v[i]; }
    part[t] = sum;
    __syncthreads();
    for (int off = 1; off < 256; off <<= 1) {
        unsigned a = (t >= off) ? part[t - off] : 0u;
        __syncthreads();
        part[t] += a;
        __syncthreads();
    }
    unsigned incl = part[t];
    unsigned excl = incl - sum;
    unsigned ranks[2] = {RS_LO, RS_HI};
    for (int k = 0; k < 2; k++) {
        unsigned Rs = ranks[k];
        if (excl < Rs && incl >= Rs) {
            unsigned cum = excl;
            for (int i = 0; i < 16; i++) {
                if (cum + v[i] >= Rs) {
                    unsigned b = (unsigned)(t * 16 + i);
                    unsigned rel = Rs - cum;
                    unsigned wb = (2u * rel <= v[i]) ? (b > 0 ? b - 1 : 0) : b;
                    if (wb > 4094u) wb = 4094u;
                    meta[k] = wb << 20;                 // window start key
                    unsigned Cs = cum;                  // samples below bucket b
                    if (wb < b) Cs -= hist[b - 1];      // extend down one bucket
                    meta[6 + k] = Cs;                   // samples below wstart
                    break;
                }
                cum += v[i];
            }
        }
    }
}

// ---------- sample_fine: fine (4-key-bin) sample hist inside coarse windows ----------
__global__ void __launch_bounds__(BLK) sample_fine_kernel(const float* __restrict__ x,
                                                          unsigned* __restrict__ ws) {
    const unsigned w0 = __builtin_amdgcn_readfirstlane(ws[OFF_META + 0]);
    const unsigned w1 = __builtin_amdgcn_readfirstlane(ws[OFF_META + 1]);
    unsigned* f0 = ws + OFF_FLO;
    unsigned* f1 = ws + OFF_FHI;
    const float4* x4 = (const float4*)x;
    const unsigned base = blockIdx.x * 11008u;
#pragma unroll
    for (int i = 0; i < 4; i++) {
        float4 v = x4[base + threadIdx.x + 256 * i];
        float f[4] = {v.x, v.y, v.z, v.w};
#pragma unroll
        for (int c = 0; c < 4; c++) {
            unsigned key = f2key(f[c]);
            unsigned d0 = key - w0;
            if (d0 < FSPAN) atomicAdd(&f0[d0 >> 2], 1u);
            unsigned d1 = key - w1;
            if (d1 < FSPAN) atomicAdd(&f1[d1 >> 2], 1u);
        }
    }
}

// ---------- csum: 1024-entry chunk sums (generic) ----------
__global__ void __launch_bounds__(BLK) csum_kernel(const unsigned* __restrict__ src,
                                                   unsigned* __restrict__ dst) {
    const unsigned* p = src + (size_t)blockIdx.x * 1024;
    int t = threadIdx.x;
    unsigned s = p[t] + p[t + 256] + p[t + 512] + p[t + 768];
    __shared__ unsigned red[256];
    red[t] = s;
    for (int off = 128; off > 0; off >>= 1) {
        __syncthreads();
        if (t < off) red[t] += red[t + off];
    }
    if (t == 0) dst[blockIdx.x] = red[0];
}

// ---------- fine_scan: pick key cut-points [kA, kA+width) at +/-M_S sample ranks -------
__global__ void __launch_bounds__(BLK) fine_scan_kernel(unsigned* __restrict__ ws) {
    __shared__ unsigned part[256];
    __shared__ unsigned sT, sC, sR;
    __shared__ unsigned sBin[2];
    const int t = threadIdx.x;
    const int tgt = blockIdx.x;
    const unsigned* cs = ws + OFF_FCS + tgt * 512;
    unsigned c0 = cs[2 * t], c1 = cs[2 * t + 1];
    unsigned gsum = c0 + c1;
    part[t] = gsum;
    __syncthreads();
    for (int off = 1; off < 256; off <<= 1) {
        unsigned a = (t >= off) ? part[t - off] : 0u;
        __syncthreads();
        part[t] += a;
        __syncthreads();
    }
    if (t == 255) sT = part[255];
    __syncthreads();
    const unsigned T = sT;
    const unsigned incl = part[t], excl = incl - gsum;   // keep in registers
    unsigned Rs = tgt ? RS_HI : RS_LO;
    unsigned Cs = ws[OFF_META + 6 + tgt];
    unsigned RsA = Rs - Cs;
    if (RsA < 1u) RsA = 1u;
    if (RsA > T) RsA = T;
    unsigned rA = (RsA > M_S) ? RsA - M_S : 1u;
    unsigned rB = RsA + M_S;
    if (rB > T) rB = T;

    for (int q = 0; q < 2; q++) {
        unsigned r = q ? rB : rA;
        if (excl < r && incl >= r) {
            if (excl + c0 >= r) { sC = 2u * t;      sR = r - excl; }
            else                { sC = 2u * t + 1u; sR = r - excl - c0; }
        }
        __syncthreads();
        unsigned chunk = sC, rr = sR;
        __syncthreads();
        const unsigned* hp = ws + OFF_FLO + (size_t)tgt * FBINS + (size_t)chunk * 1024;
        unsigned w[4];
        unsigned s2 = 0u;
#pragma unroll
        for (int i = 0; i < 4; i++) { w[i] = hp[t * 4 + i]; s2 += w[i]; }
        part[t] = s2;
        __syncthreads();
        for (int off = 1; off < 256; off <<= 1) {
            unsigned a = (t >= off) ? part[t - off] : 0u;
            __syncthreads();
            part[t] += a;
            __syncthreads();
        }
        unsigned incl2 = part[t], excl2 = incl2 - s2;
        if (excl2 < rr && incl2 >= rr) {
            unsigned cum = excl2;
            for (int i = 0; i < 4; i++) {
                if (cum + w[i] >= rr) { sBin[q] = chunk * 1024u + (unsigned)(t * 4 + i); break; }
                cum += w[i];
            }
        }
        __syncthreads();
    }
    if (t == 0) {
        unsigned wstart = ws[OFF_META + tgt];
        unsigned kA = wstart + sBin[0] * 4u;
        unsigned kB = wstart + (sBin[1] + 1u) * 4u;
        unsigned width = kB - kA;
        if (width > WMAX) width = WMAX;
        ws[OFF_META + 2 + 2 * tgt] = kA;
        ws[OFF_META + 3 + 2 * tgt] = width;
    }
}

// ---------- passA: exact below-kA counts + narrow-window element hist ----------
__device__ __forceinline__ void passA_elem(float f, unsigned kAlo, unsigned wLo,
                                           unsigned kAhi, unsigned wHi,
                                           unsigned& cLo, unsigned& cHi,
                                           unsigned* hLo, unsigned* hHi) {
    unsigned key = f2key(f);
    cLo += (key < kAlo) ? 1u : 0u;
    cHi += (key < kAhi) ? 1u : 0u;
    unsigned d0 = key - kAlo;
    if (d0 < wLo) atomicAdd(&hLo[d0], 1u);
    unsigned d1 = key - kAhi;
    if (d1 < wHi) atomicAdd(&hHi[d1], 1u);
}

__global__ void __launch_bounds__(BLK) passA_kernel(const float* __restrict__ x,
                                                    unsigned* __restrict__ ws) {
    const unsigned kAlo = __builtin_amdgcn_readfirstlane(ws[OFF_META + 2]);
    const unsigned wLo  = __builtin_amdgcn_readfirstlane(ws[OFF_META + 3]);
    const unsigned kAhi = __builtin_amdgcn_readfirstlane(ws[OFF_META + 4]);
    const unsigned wHi  = __builtin_amdgcn_readfirstlane(ws[OFF_META + 5]);
    unsigned* hLo = ws + OFF_WLO;
    unsigned* hHi = ws + OFF_WHI;

    const float4* x4 = (const float4*)x;
    unsigned cLo = 0u, cHi = 0u;

    for (unsigned tile = blockIdx.x; tile < NTILES; tile += gridDim.x) {
        const float4* p = x4 + (size_t)tile * 1024u + threadIdx.x;
        float4 a = p[0];
        float4 b = p[256];
        float4 c = p[512];
        float4 d = p[768];
        passA_elem(a.x, kAlo, wLo, kAhi, wHi, cLo, cHi, hLo, hHi);
        passA_elem(a.y, kAlo, wLo, kAhi, wHi, cLo, cHi, hLo, hHi);
        passA_elem(a.z, kAlo, wLo, kAhi, wHi, cLo, cHi, hLo, hHi);
        passA_elem(a.w, kAlo, wLo, kAhi, wHi, cLo, cHi, hLo, hHi);
        passA_elem(b.x, kAlo, wLo, kAhi, wHi, cLo, cHi, hLo, hHi);
        passA_elem(b.y, kAlo, wLo, kAhi, wHi, cLo, cHi, hLo, hHi);
        passA_elem(b.z, kAlo, wLo, kAhi, wHi, cLo, cHi, hLo, hHi);
        passA_elem(b.w, kAlo, wLo, kAhi, wHi, cLo, cHi, hLo, hHi);
        passA_elem(c.x, kAlo, wLo, kAhi, wHi, cLo, cHi, hLo, hHi);
        passA_elem(c.y, kAlo, wLo, kAhi, wHi, cLo, cHi, hLo, hHi);
        passA_elem(c.z, kAlo, wLo, kAhi, wHi, cLo, cHi, hLo, hHi);
        passA_elem(c.w, kAlo, wLo, kAhi, wHi, cLo, cHi, hLo, hHi);
        passA_elem(d.x, kAlo, wLo, kAhi, wHi, cLo, cHi, hLo, hHi);
        passA_elem(d.y, kAlo, wLo, kAhi, wHi, cLo, cHi, hLo, hHi);
        passA_elem(d.z, kAlo, wLo, kAhi, wHi, cLo, cHi, hLo, hHi);
        passA_elem(d.w, kAlo, wLo, kAhi, wHi, cLo, cHi, hLo, hHi);
    }

    __shared__ unsigned red[256];
    red[threadIdx.x] = cLo;
    for (int off = 128; off > 0; off >>= 1) {
        __syncthreads();
        if (threadIdx.x < off) red[threadIdx.x] += red[threadIdx.x + off];
    }
    if (threadIdx.x == 0) atomicAdd(&ws[OFF_CLO + (blockIdx.x & 63)], red[0]);
    __syncthreads();
    red[threadIdx.x] = cHi;
    for (int off = 128; off > 0; off >>= 1) {
        __syncthreads();
        if (threadIdx.x < off) red[threadIdx.x] += red[threadIdx.x + off];
    }
    if (threadIdx.x == 0) atomicAdd(&ws[OFF_CHI + (blockIdx.x & 63)], red[0]);
}

// ---------- scanB: exact rank select inside the narrow window -> thresholds ----------
__global__ void __launch_bounds__(BLK) scanB_kernel(unsigned* __restrict__ ws) {
    __shared__ unsigned part[256];
    __shared__ unsigned s_C, s_chunk, s_r;
    const int t = threadIdx.x;
    const int tgt = blockIdx.x;
    float* thr = (float*)(ws + OFF_THR);

    part[t] = (t < 64) ? ws[(tgt ? OFF_CHI : OFF_CLO) + t] : 0u;
    for (int off = 128; off > 0; off >>= 1) {
        __syncthreads();
        if (t < off) part[t] += part[t + off];
    }
    if (t == 0) s_C = part[0];
    __syncthreads();
    const unsigned RANK = tgt ? RANK_HI : RANK_LO;
    const unsigned R = RANK - s_C;    // 1-indexed residual inside window
    __syncthreads();

    const unsigned* cs = ws + OFF_WCS + tgt * 512;
    unsigned c0 = cs[2 * t], c1 = cs[2 * t + 1];
    unsigned gsum = c0 + c1;
    part[t] = gsum;
    __syncthreads();
    for (int off = 1; off < 256; off <<= 1) {
        unsigned a = (t >= off) ? part[t - off] : 0u;
        __syncthreads();
        part[t] += a;
        __syncthreads();
    }
    unsigned incl = part[t], excl = incl - gsum;
    if (excl < R && incl >= R) {
        if (excl + c0 >= R) { s_chunk = 2u * t;      s_r = R - excl; }
        else                { s_chunk = 2u * t + 1u; s_r = R - excl - c0; }
    }
    __syncthreads();
    unsigned chunk = s_chunk, rr = s_r;
    __syncthreads();

    const unsigned* hp = ws + (tgt ? OFF_WHI : OFF_WLO) + (size_t)chunk * 1024;
    unsigned w[4];
    unsigned s2 = 0u;
#pragma unroll
    for (int i = 0; i < 4; i++) { w[i] = hp[t * 4 + i]; s2 += w[i]; }
    part[t] = s2;
    __syncthreads();
    for (int off = 1; off < 256; off <<= 1) {
        unsigned a = (t >= off) ? part[t - off] : 0u;
        __syncthreads();
        part[t] += a;
        __syncthreads();
    }
    unsigned incl2 = part[t], excl2 = incl2 - s2;
    if (excl2 < rr && incl2 >= rr) {
        unsigned cum = excl2;
        for (int i = 0; i < 4; i++) {
            if (cum + w[i] >= rr) {
                unsigned key = ws[OFF_META + 2 + 2 * tgt] + chunk * 1024u + (unsigned)(t * 4 + i);
                thr[tgt] = key2f(key);
                break;
            }
            cum += w[i];
        }
    }
}

// ---------- quant: pure streaming dual qdq, 4x ILP, NT stores ----------
__global__ void __launch_bounds__(BLK) quant_kernel(const float* __restrict__ x,
                                                    const float* __restrict__ sl_,
                                                    const float* __restrict__ zl_,
                                                    const float* __restrict__ sh_,
                                                    const float* __restrict__ zh_,
                                                    const unsigned* __restrict__ ws,
                                                    float* __restrict__ out) {
    const float lowT  = __uint_as_float(__builtin_amdgcn_readfirstlane(ws[OFF_THR + 0]));
    const float highT = __uint_as_float(__builtin_amdgcn_readfirstlane(ws[OFF_THR + 1]));
    const float4* x4 = (const float4*)x;
    vfloat4* o4 = (vfloat4*)out;

    for (unsigned tile = blockIdx.x; tile < NTILES; tile += gridDim.x) {
        const size_t base = (size_t)tile * 1024u + threadIdx.x;
        float4 vv[4];
        vv[0] = x4[base];
        vv[1] = x4[base + 256];
        vv[2] = x4[base + 512];
        vv[3] = x4[base + 768];
#pragma unroll
        for (int u = 0; u < 4; u++) {
            unsigned j = (unsigned)(base + 256u * u);
            unsigned row = j / COLS4;
            float sl = sl_[row], zl = zl_[row];
            float sh = sh_[row], zh = zh_[row];
            float in[4] = {vv[u].x, vv[u].y, vv[u].z, vv[u].w};
            float r[4];
#pragma unroll
            for (int c = 0; c < 4; c++) {
                float xx = in[c];
                bool m = (xx > lowT) && (xx < highT);
                r[c] = qdq(xx, m, sl, zl, sh, zh);
            }
            vfloat4 rv = {r[0], r[1], r[2], r[3]};
            __builtin_nontemporal_store(rv, &o4[j]);
        }
    }
}

extern "C" void kernel_launch(void* const* d_in, const int* in_sizes, int n_in,
                              void* d_out, int out_size, void* d_ws, size_t ws_size,
                              hipStream_t stream) {
    const float* x  = (const float*)d_in[0];
    const float* sl = (const float*)d_in[1];
    const float* zl = (const float*)d_in[2];
    const float* sh = (const float*)d_in[3];
    const float* zh = (const float*)d_in[4];
    float* out = (float*)d_out;
    unsigned* ws = (unsigned*)d_ws;

    (void)hipMemsetAsync(d_ws, 0, (size_t)WS_WORDS * 4, stream);   // ~8.4 MB

    sample_kernel<<<1024, BLK, 0, stream>>>(x, ws);
    scan_sample_kernel<<<1, BLK, 0, stream>>>(ws);
    sample_fine_kernel<<<1024, BLK, 0, stream>>>(x, ws);
    csum_kernel<<<1024, BLK, 0, stream>>>(ws + OFF_FLO, ws + OFF_FCS);
    fine_scan_kernel<<<2, BLK, 0, stream>>>(ws);
    passA_kernel<<<GRID, BLK, 0, stream>>>(x, ws);
    csum_kernel<<<1024, BLK, 0, stream>>>(ws + OFF_WLO, ws + OFF_WCS);
    scanB_kernel<<<2, BLK, 0, stream>>>(ws);
    quant_kernel<<<GRID, BLK, 0, stream>>>(x, sl, zl, sh, zh, ws, out);
}